// Round 1
// baseline (154.889 us; speedup 1.0000x reference)
//
#include <hip/hip_runtime.h>
#include <float.h>

#define B_   2
#define F_   8192
#define Q_   4096
#define PTS  256         // threads per scan block
#define PPT  4           // points per thread in scan (2 packed fp32 pairs)

typedef float f2 __attribute__((ext_vector_type(2)));
typedef float f4u __attribute__((ext_vector_type(4), aligned(4)));
typedef unsigned int uint;

__device__ __forceinline__ f2 clamp01(f2 x) {
    f2 z = {0.f, 0.f}, o = {1.f, 1.f};
    return __builtin_elementwise_min(__builtin_elementwise_max(x, z), o);
}

// ---------------------------------------------------------------------------
// Exact reference-order Ericson barycentrics. Contract OFF: every op rounds
// exactly like the numpy reference; op order matches term-for-term.
// jnp.select first-true-wins priority; _safe_div(n,d) = n/(d==0?1:d).
__device__ __forceinline__ void bary_uvw(
    float ax, float ay, float az,
    float bx, float by, float bz,
    float cx, float cy, float cz,
    float px, float py, float pz,
    float& u, float& v, float& w)
{
#pragma clang fp contract(off)
    float abx = bx - ax, aby = by - ay, abz = bz - az;
    float acx = cx - ax, acy = cy - ay, acz = cz - az;
    float apx = px - ax, apy = py - ay, apz = pz - az;
    float d1 = abx*apx + aby*apy + abz*apz;
    float d2 = acx*apx + acy*apy + acz*apz;
    float bpx = px - bx, bpy = py - by, bpz = pz - bz;
    float d3 = abx*bpx + aby*bpy + abz*bpz;
    float d4 = acx*bpx + acy*bpy + acz*bpz;
    float qx = px - cx, qy = py - cy, qz = pz - cz;
    float d5 = abx*qx + aby*qy + abz*qz;
    float d6 = acx*qx + acy*qy + acz*qz;
    float vc = d1*d4 - d3*d2;
    float vb = d5*d2 - d1*d6;
    float va = d3*d6 - d5*d4;

    bool c1 = (d1 <= 0.f) && (d2 <= 0.f);
    bool c2 = (d3 >= 0.f) && (d4 <= d3);
    bool c3 = (vc <= 0.f) && (d1 >= 0.f) && (d3 <= 0.f);
    bool c4 = (d6 >= 0.f) && (d5 <= d6);
    bool c5 = (vb <= 0.f) && (d2 >= 0.f) && (d6 <= 0.f);
    bool c6 = (va <= 0.f) && (d4 >= d3) && (d5 >= d6);

    bool e1 = c1;
    bool p1 = !c1;
    bool e2 = p1 && c2;
    bool p2 = p1 && !c2;
    bool e3 = p2 && c3;
    bool p3 = p2 && !c3;
    bool e4 = p3 && c4;
    bool p4 = p3 && !c4;
    bool e5 = p4 && c5;
    bool p5 = p4 && !c5;
    bool e6 = p5 && c6;

    float d43 = d4 - d3;
    float d56 = d5 - d6;
    float n  = e3 ? d1        : (e5 ? d2        : (e6 ? d43         : 1.f));
    float dd = e3 ? (d1 - d3) : (e5 ? (d2 - d6) : (e6 ? (d43 + d56) : (va + vb + vc)));
    dd = (dd == 0.f) ? 1.f : dd;   // _safe_div
    float t = n / dd;

    float vi = vb * t;
    float wi = vc * t;
    u = e1 ? 1.f : (e2 ? 0.f : (e3 ? 1.f - t : (e4 ? 0.f : (e5 ? 1.f - t : (e6 ? 0.f     : 1.f - vi - wi)))));
    v = e1 ? 0.f : (e2 ? 1.f : (e3 ? t       : (e4 ? 0.f : (e5 ? 0.f     : (e6 ? 1.f - t : vi)))));
    w = e1 ? 0.f : (e2 ? 0.f : (e3 ? 0.f     : (e4 ? 1.f : (e5 ? t       : (e6 ? t       : wi)))));
}

// Cheap nomination distance^2, one point-pair vs one triangle.
// May return tiny negative values (rounding); nomination uses SIGNED int keys,
// so the float-bit ordering is still correct for all non-negative values and
// near-zero negatives sort first (harmless: exact tail decides).
__device__ __forceinline__ f2 pair_dist(
    f2 px, f2 py, f2 pz,
    float ax, float ay, float az,
    float abx, float aby, float abz,
    float acx, float acy, float acz,
    float daa, float dcc, float dac, float dbc, float kk,
    float rdaa, float rdcc, float rdbc, float rnn)
{
    f2 apx = px - ax, apy = py - ay, apz = pz - az;
    f2 d1  = abx*apx + aby*apy + abz*apz;
    f2 d2  = acx*apx + acy*apy + acz*apz;
    f2 app = apx*apx + apy*apy + apz*apz;

    f2 t1 = d1*dcc - d2*dac;
    f2 t2 = d2*daa - d1*dac;
    f2 t12n = 1.f - (t1 + t2)*rnn;
    f2 sgr  = (d1*t1 + d2*t2)*rnn;
    f2 ins  = __builtin_elementwise_min(__builtin_elementwise_min(t1, t2), t12n);

    f2 td1 = d1 + d1;
    f2 tab = clamp01(d1 * rdaa);
    f2 rab = tab*(td1 - tab*daa);
    f2 tac = clamp01(d2 * rdcc);
    f2 rac = tac*((d2 + d2) - tac*dcc);
    f2 d43 = (d2 - d1) + kk;
    f2 sbc = clamp01(d43 * rdbc);
    f2 rbc = (td1 - daa) + sbc*((d43 + d43) - sbc*dbc);
    f2 rmax = __builtin_elementwise_max(__builtin_elementwise_max(rab, rac), rbc);

    f2 red;
    red.x = (ins.x >= 0.f) ? sgr.x : rmax.x;
    red.y = (ins.y >= 0.f) ? sgr.y : rmax.y;
    return app - red;
}

// ---------------------------------------------------------------------------
// Scan: cheap loop nominates top-2/chunk (sortable SIGNED int keys); TAIL
// exact-evaluates both nominees per point with the np-order contract-off
// formula reading RAW a,b,c from LDS (bit-identical inputs => bit-identical
// d^2) and emits one (d_exact_bits, face) pair per (point, chunk). Finalize
// needs no candidate gathers. NO cheap-distance filtering anywhere (R5).
//
// FCv = triangles per chunk (power of 2). NCv = F_/FCv chunks.
// FCv=32 gives 2048 workgroups -> 8 blocks/CU -> 32 waves/CU residency.
template<int FCv>
__global__ __launch_bounds__(PTS, 8) void scan_kernel(
    const float* __restrict__ tri, const float* __restrict__ pts,
    uint2* __restrict__ keys)
{
    constexpr int NCv = F_ / FCv;
    constexpr int IM  = ~(FCv - 1);       // key mask: keep distance bits, low bits hold face
    // per-tri 6 x float4: [0] a|daa  [1] ab|dcc  [2] ac|dac  [3] recips  [4] b  [5] c
    __shared__ float4 S[FCv * 6];
    const int tid = threadIdx.x;
    const int pb = blockIdx.x, cb = blockIdx.y, bb = blockIdx.z;

    if (tid < FCv) {   // one thread stages one triangle fully
        const float* g = tri + ((size_t)bb * F_ + (size_t)cb * FCv + tid) * 9;
        float ax = g[0], ay = g[1], az = g[2];
        float bx = g[3], by = g[4], bz = g[5];
        float cx = g[6], cy = g[7], cz = g[8];
        float abx = bx - ax, aby = by - ay, abz = bz - az;
        float acx = cx - ax, acy = cy - ay, acz = cz - az;
        float daa = abx*abx + aby*aby + abz*abz;
        float dcc = acx*acx + acy*acy + acz*acz;
        float dac = abx*acx + aby*acy + abz*acz;
        float dbc = daa + dcc - 2.f*dac;
        float nn  = daa*dcc - dac*dac;
        S[tid*6 + 0] = make_float4(ax, ay, az, daa);
        S[tid*6 + 1] = make_float4(abx, aby, abz, dcc);
        S[tid*6 + 2] = make_float4(acx, acy, acz, dac);
        S[tid*6 + 3] = make_float4(1.f/daa, 1.f/dcc, 1.f/dbc, 1.f/nn);
        S[tid*6 + 4] = make_float4(bx, by, bz, 0.f);
        S[tid*6 + 5] = make_float4(cx, cy, cz, 0.f);
    }
    __syncthreads();

    const int q0 = pb * (PTS * PPT) + tid * PPT;
    const float* p0 = pts + ((size_t)bb * Q_ + q0) * 3;
    f4u l0 = *(const f4u*)(p0);
    f4u l1 = *(const f4u*)(p0 + 4);
    f4u l2 = *(const f4u*)(p0 + 8);
    f2 pxA = {l0.x, l0.w}, pyA = {l0.y, l1.x}, pzA = {l0.z, l1.y};
    f2 pxB = {l1.z, l2.y}, pyB = {l1.w, l2.z}, pzB = {l2.x, l2.w};

    int k00 = 0x7FFFFFFF, k01 = 0x7FFFFFFF;
    int k10 = 0x7FFFFFFF, k11 = 0x7FFFFFFF;
    int k20 = 0x7FFFFFFF, k21 = 0x7FFFFFFF;
    int k30 = 0x7FFFFFFF, k31 = 0x7FFFFFFF;
    #pragma unroll 2
    for (int fl = 0; fl < FCv; ++fl) {
        float4 c0 = S[fl*6 + 0];
        float4 c1 = S[fl*6 + 1];
        float4 c2 = S[fl*6 + 2];
        float4 c3 = S[fl*6 + 3];
        float daa = c0.w, dcc = c1.w, dac = c2.w;
        float dbc = daa + dcc - 2.f*dac;
        float kk  = daa - dac;

        f2 dA = pair_dist(pxA, pyA, pzA, c0.x, c0.y, c0.z,
                          c1.x, c1.y, c1.z, c2.x, c2.y, c2.z,
                          daa, dcc, dac, dbc, kk, c3.x, c3.y, c3.z, c3.w);
        f2 dB = pair_dist(pxB, pyB, pzB, c0.x, c0.y, c0.z,
                          c1.x, c1.y, c1.z, c2.x, c2.y, c2.z,
                          daa, dcc, dac, dbc, kk, c3.x, c3.y, c3.z, c3.w);

        int kA0 = (__float_as_int(dA.x) & IM) | fl;
        int kA1 = (__float_as_int(dA.y) & IM) | fl;
        int kB0 = (__float_as_int(dB.x) & IM) | fl;
        int kB1 = (__float_as_int(dB.y) & IM) | fl;
        int lo, hi;
        lo = min(k00, kA0); hi = max(k00, kA0); k00 = lo; k01 = min(k01, hi);
        lo = min(k10, kA1); hi = max(k10, kA1); k10 = lo; k11 = min(k11, hi);
        lo = min(k20, kB0); hi = max(k20, kB0); k20 = lo; k21 = min(k21, hi);
        lo = min(k30, kB1); hi = max(k30, kB1); k30 = lo; k31 = min(k31, hi);
    }

    // TAIL: exact np-order eval of both nominees per point (raw coords from LDS)
    float pxs[4] = {l0.x, l0.w, l1.z, l2.y};
    float pys[4] = {l0.y, l1.x, l1.w, l2.z};
    float pzs[4] = {l0.z, l1.y, l2.x, l2.w};
    int kk0[4] = {k00, k10, k20, k30};
    int kk1[4] = {k01, k11, k21, k31};

    #pragma unroll
    for (int p = 0; p < 4; ++p) {
        float px = pxs[p], py = pys[p], pz = pzs[p];
        float dbest = FLT_MAX; int fbest = 0x7FFFFFFF;
        #pragma unroll
        for (int j = 0; j < 2; ++j) {
            int lf = (j == 0 ? kk0[p] : kk1[p]) & (FCv - 1);
            float4 ra = S[lf*6 + 0];
            float4 rb = S[lf*6 + 4];
            float4 rc = S[lf*6 + 5];
            float u, v, w;
            bary_uvw(ra.x, ra.y, ra.z, rb.x, rb.y, rb.z, rc.x, rc.y, rc.z,
                     px, py, pz, u, v, w);
            float d2v;
            {
#pragma clang fp contract(off)
                float cpx = u*ra.x + v*rb.x + w*rc.x;
                float cpy = u*ra.y + v*rb.y + w*rc.y;
                float cpz = u*ra.z + v*rb.z + w*rc.z;
                float dx = cpx - px, dy = cpy - py, dz = cpz - pz;
                d2v = dx*dx + dy*dy + dz*dz;
            }
            int face = cb * FCv + lf;
            if (d2v < dbest || (d2v == dbest && face < fbest)) { dbest = d2v; fbest = face; }
        }
        // point-major [b][q][chunk]: finalize reads coalesced uint4
        keys[((size_t)bb * Q_ + q0 + p) * NCv + cb] = make_uint2(__float_as_uint(dbest), (uint)fbest);
    }
}

// ---------------------------------------------------------------------------
// Finalize: one WAVE per point; lane l loads 2 chunks per uint4 (coalesced),
// NCv=256 -> two uint4 per lane. Wave lex-(d,face) reduce == jnp.argmin first
// occurrence (true winner is the exact-min of its chunk's top-2 pair, so it
// is the chunk representative). Lane 0 epilogue, contract-off np-order.
template<int NCv>
__global__ __launch_bounds__(256) void finalize_kernel(
    const float* __restrict__ tri, const float* __restrict__ pts,
    const float* __restrict__ nrm, const float* __restrict__ cmp,
    const int* __restrict__ faces,
    const uint2* __restrict__ keys,
    float* __restrict__ out)
{
#pragma clang fp contract(off)
    const int lane = threadIdx.x & 63;
    const int t = blockIdx.x * 4 + (threadIdx.x >> 6);
    const int bb = t >> 12;            // Q_ = 4096

    const uint4* kp = (const uint4*)keys + (size_t)t * (NCv/2);
    uint4 K = kp[lane];
    float dbest = __uint_as_float(K.x); int fbest = (int)K.y;
    float d1v   = __uint_as_float(K.z); int f1v   = (int)K.w;
    if (d1v < dbest || (d1v == dbest && f1v < fbest)) { dbest = d1v; fbest = f1v; }
    if (NCv == 256) {
        uint4 K2 = kp[lane + 64];
        float d2v = __uint_as_float(K2.x); int f2v = (int)K2.y;
        if (d2v < dbest || (d2v == dbest && f2v < fbest)) { dbest = d2v; fbest = f2v; }
        float d3v = __uint_as_float(K2.z); int f3v = (int)K2.w;
        if (d3v < dbest || (d3v == dbest && f3v < fbest)) { dbest = d3v; fbest = f3v; }
    }
    for (int off = 32; off > 0; off >>= 1) {
        float od = __shfl_down(dbest, off);
        int   of = __shfl_down(fbest, off);
        if (od < dbest || (od == dbest && of < fbest)) { dbest = od; fbest = of; }
    }
    if (lane != 0) return;

    const float* pp = pts + (size_t)t * 3;
    float px = pp[0], py = pp[1], pz = pp[2];

    const int bestf = fbest;
    const float* tg = tri + ((size_t)bb * F_ + bestf) * 9;
    const float* ng = nrm + ((size_t)bb * F_ + bestf) * 9;
    const float* cg = cmp + ((size_t)bb * F_ + bestf) * 9;
    f4u TA = *(const f4u*)(tg), TB = *(const f4u*)(tg + 4);
    float TC = tg[8];
    f4u NA = *(const f4u*)(ng), NB = *(const f4u*)(ng + 4);
    float NCs = ng[8];
    f4u CA = *(const f4u*)(cg), CB = *(const f4u*)(cg + 4);
    float CC = cg[8];

    float u, v, w;
    bary_uvw(TA.x, TA.y, TA.z, TA.w, TB.x, TB.y, TB.z, TB.w, TC,
             px, py, pz, u, v, w);
    u = fminf(fmaxf(u, 0.f), 1.f);
    v = fminf(fmaxf(v, 0.f), 1.f);
    w = fminf(fmaxf(w, 0.f), 1.f);

    float cpx = u * TA.x + v * TA.w + w * TB.z;
    float cpy = u * TA.y + v * TB.x + w * TB.w;
    float cpz = u * TA.z + v * TB.y + w * TC;
    float nx  = u * NA.x + v * NA.w + w * NB.z;
    float ny  = u * NA.y + v * NB.x + w * NB.w;
    float nz  = u * NA.z + v * NB.y + w * NCs;
    float mx  = u * CA.x + v * CA.w + w * CB.z;
    float my  = u * CA.y + v * CB.x + w * CB.w;
    float mz  = u * CA.z + v * CB.y + w * CC;

    const size_t S3 = (size_t)B_ * Q_ * 3;
    out[(size_t)t * 3 + 0] = cpx - px;
    out[(size_t)t * 3 + 1] = cpy - py;
    out[(size_t)t * 3 + 2] = cpz - pz;
    out[S3 + (size_t)t * 3 + 0] = nx;
    out[S3 + (size_t)t * 3 + 1] = ny;
    out[S3 + (size_t)t * 3 + 2] = nz;
    out[2 * S3 + (size_t)t * 3 + 0] = mx;
    out[2 * S3 + (size_t)t * 3 + 1] = my;
    out[2 * S3 + (size_t)t * 3 + 2] = mz;

    int k = 0; float mm = u;
    if (v > mm) { mm = v; k = 1; }
    if (w > mm) { k = 2; }
    out[3 * S3 + t] = (float)faces[((size_t)bb * F_ + bestf) * 3 + k];
}

extern "C" void kernel_launch(void* const* d_in, const int* in_sizes, int n_in,
                              void* d_out, int out_size, void* d_ws, size_t ws_size,
                              hipStream_t stream) {
    const float* tri   = (const float*)d_in[0];
    const float* pts   = (const float*)d_in[1];
    const float* nrm   = (const float*)d_in[2];
    const float* cmp   = (const float*)d_in[3];
    const int*   faces = (const int*)d_in[4];
    float* out = (float*)d_out;

    uint2* keys = (uint2*)d_ws;   // [B][Q][NC] exact (d_bits, face) per chunk

    const size_t need256 = (size_t)B_ * Q_ * 256 * sizeof(uint2);   // 16 MiB
    if (ws_size >= need256) {
        // FC=32 -> NC=256 -> 2048 WGs -> 8 blocks/CU -> full 32-wave residency
        dim3 g1(Q_ / (PTS * PPT), 256, B_);
        scan_kernel<32><<<g1, PTS, 0, stream>>>(tri, pts, keys);
        finalize_kernel<256><<<(B_ * Q_) / 4, 256, 0, stream>>>(
            tri, pts, nrm, cmp, faces, keys, out);
    } else {
        // fallback: proven NC=128 config (8 MiB workspace)
        dim3 g1(Q_ / (PTS * PPT), 128, B_);
        scan_kernel<64><<<g1, PTS, 0, stream>>>(tri, pts, keys);
        finalize_kernel<128><<<(B_ * Q_) / 4, 256, 0, stream>>>(
            tri, pts, nrm, cmp, faces, keys, out);
    }
}

// Round 2
// 138.158 us; speedup vs baseline: 1.1211x; 1.1211x over previous
//
#include <hip/hip_runtime.h>
#include <float.h>

#define B_   2
#define F_   8192
#define Q_   4096
#define NC   128         // F-chunks
#define FC   (F_/NC)     // 64 triangles per chunk -> 6-bit local index in key
#define PTS  256         // threads per scan block
#define PPT  4           // points per thread in scan

typedef float f2 __attribute__((ext_vector_type(2)));
typedef float f4u __attribute__((ext_vector_type(4), aligned(4)));
typedef unsigned int uint;

// ---------------------------------------------------------------------------
// Packed-f32 (2 triangles per op) helpers. CDNA3/4 have full-rate
// V_PK_FMA_F32 / V_PK_MUL_F32 / V_PK_ADD_F32 on 64-bit VGPR pairs; the
// compiler scalarizes ext_vector f2 math, so force them. No modifiers used
// (subtractions come from pre-negated constants), minimizing asm risk.
__device__ __forceinline__ f2 pk_fma(f2 a, f2 b, f2 c) {
    f2 d; asm("v_pk_fma_f32 %0, %1, %2, %3" : "=v"(d) : "v"(a), "v"(b), "v"(c)); return d;
}
__device__ __forceinline__ f2 pk_mul(f2 a, f2 b) {
    f2 d; asm("v_pk_mul_f32 %0, %1, %2" : "=v"(d) : "v"(a), "v"(b)); return d;
}
__device__ __forceinline__ f2 pk_add(f2 a, f2 b) {
    f2 d; asm("v_pk_add_f32 %0, %1, %2" : "=v"(d) : "v"(a), "v"(b)); return d;
}

__device__ __forceinline__ f2 clamp01(f2 x) {
    f2 z = {0.f, 0.f}, o = {1.f, 1.f};
    return __builtin_elementwise_min(__builtin_elementwise_max(x, z), o);
}

// ---------------------------------------------------------------------------
// Exact reference-order Ericson barycentrics. Contract OFF: every op rounds
// exactly like the numpy reference; op order matches term-for-term.
// jnp.select first-true-wins priority; _safe_div(n,d) = n/(d==0?1:d).
__device__ __forceinline__ void bary_uvw(
    float ax, float ay, float az,
    float bx, float by, float bz,
    float cx, float cy, float cz,
    float px, float py, float pz,
    float& u, float& v, float& w)
{
#pragma clang fp contract(off)
    float abx = bx - ax, aby = by - ay, abz = bz - az;
    float acx = cx - ax, acy = cy - ay, acz = cz - az;
    float apx = px - ax, apy = py - ay, apz = pz - az;
    float d1 = abx*apx + aby*apy + abz*apz;
    float d2 = acx*apx + acy*apy + acz*apz;
    float bpx = px - bx, bpy = py - by, bpz = pz - bz;
    float d3 = abx*bpx + aby*bpy + abz*bpz;
    float d4 = acx*bpx + acy*bpy + acz*bpz;
    float qx = px - cx, qy = py - cy, qz = pz - cz;
    float d5 = abx*qx + aby*qy + abz*qz;
    float d6 = acx*qx + acy*qy + acz*qz;
    float vc = d1*d4 - d3*d2;
    float vb = d5*d2 - d1*d6;
    float va = d3*d6 - d5*d4;

    bool c1 = (d1 <= 0.f) && (d2 <= 0.f);
    bool c2 = (d3 >= 0.f) && (d4 <= d3);
    bool c3 = (vc <= 0.f) && (d1 >= 0.f) && (d3 <= 0.f);
    bool c4 = (d6 >= 0.f) && (d5 <= d6);
    bool c5 = (vb <= 0.f) && (d2 >= 0.f) && (d6 <= 0.f);
    bool c6 = (va <= 0.f) && (d4 >= d3) && (d5 >= d6);

    bool e1 = c1;
    bool p1 = !c1;
    bool e2 = p1 && c2;
    bool p2 = p1 && !c2;
    bool e3 = p2 && c3;
    bool p3 = p2 && !c3;
    bool e4 = p3 && c4;
    bool p4 = p3 && !c4;
    bool e5 = p4 && c5;
    bool p5 = p4 && !c5;
    bool e6 = p5 && c6;

    float d43 = d4 - d3;
    float d56 = d5 - d6;
    float n  = e3 ? d1        : (e5 ? d2        : (e6 ? d43         : 1.f));
    float dd = e3 ? (d1 - d3) : (e5 ? (d2 - d6) : (e6 ? (d43 + d56) : (va + vb + vc)));
    dd = (dd == 0.f) ? 1.f : dd;   // _safe_div
    float t = n / dd;

    float vi = vb * t;
    float wi = vc * t;
    u = e1 ? 1.f : (e2 ? 0.f : (e3 ? 1.f - t : (e4 ? 0.f : (e5 ? 1.f - t : (e6 ? 0.f     : 1.f - vi - wi)))));
    v = e1 ? 0.f : (e2 ? 1.f : (e3 ? t       : (e4 ? 0.f : (e5 ? 0.f     : (e6 ? 1.f - t : vi)))));
    w = e1 ? 0.f : (e2 ? 0.f : (e3 ? 0.f     : (e4 ? 1.f : (e5 ? t       : (e6 ? t       : wi)))));
}

// ---------------------------------------------------------------------------
// Cheap nomination distance^2: ONE point vs a PAIR of triangles (f2 lanes =
// triangles 2j, 2j+1). All triangle constants are f2 from LDS; point coords
// are pre-broadcast f2. Nomination-only: rounding freedom, exact tail decides.
__device__ __forceinline__ f2 tri_pair_dist(
    f2 px, f2 py, f2 pz,
    f2 nax, f2 nay, f2 naz,
    f2 abx, f2 aby, f2 abz,
    f2 acx, f2 acy, f2 acz,
    f2 daa, f2 dcc, f2 ndac,
    f2 ndaa, f2 ndcc, f2 ndbc,
    f2 kk,  f2 rdaa, f2 rdcc, f2 rdbc, f2 rnn, f2 nn, f2 NEG1)
{
    f2 apx = pk_add(px, nax), apy = pk_add(py, nay), apz = pk_add(pz, naz);
    f2 d1  = pk_fma(abz, apz, pk_fma(aby, apy, pk_mul(abx, apx)));
    f2 d2  = pk_fma(acz, apz, pk_fma(acy, apy, pk_mul(acx, apx)));
    f2 app = pk_fma(apz, apz, pk_fma(apy, apy, pk_mul(apx, apx)));

    f2 t1  = pk_fma(d1, dcc, pk_mul(d2, ndac));   // d1*dcc - d2*dac
    f2 t2  = pk_fma(d2, daa, pk_mul(d1, ndac));   // d2*daa - d1*dac
    f2 s12 = pk_add(t1, t2);
    f2 t12n = pk_fma(s12, NEG1, nn);              // nn - (t1+t2)  (sign-equiv test)
    f2 sgr = pk_mul(pk_fma(d2, t2, pk_mul(d1, t1)), rnn);
    f2 ins = __builtin_elementwise_min(__builtin_elementwise_min(t1, t2), t12n);

    f2 td1 = pk_add(d1, d1);
    f2 tab = clamp01(pk_mul(d1, rdaa));
    f2 rab = pk_mul(tab, pk_fma(tab, ndaa, td1)); // tab*(2d1 - tab*daa)
    f2 td2 = pk_add(d2, d2);
    f2 tac = clamp01(pk_mul(d2, rdcc));
    f2 rac = pk_mul(tac, pk_fma(tac, ndcc, td2)); // tac*(2d2 - tac*dcc)
    f2 d43 = pk_add(pk_fma(d1, NEG1, d2), kk);    // (d2-d1) + (daa-dac)
    f2 sbc = clamp01(pk_mul(d43, rdbc));
    f2 rbc = pk_add(pk_add(td1, ndaa),
                    pk_mul(sbc, pk_fma(sbc, ndbc, pk_add(d43, d43))));
    f2 rmax = __builtin_elementwise_max(__builtin_elementwise_max(rab, rac), rbc);

    f2 red;
    red.x = (ins.x >= 0.f) ? sgr.x : rmax.x;
    red.y = (ins.y >= 0.f) ? sgr.y : rmax.y;
    return pk_fma(red, NEG1, app);                // app - red
}

// ---------------------------------------------------------------------------
// Scan: cheap packed loop nominates top-2/chunk (sortable SIGNED int keys);
// TAIL exact-evaluates both nominees per point with the np-order contract-off
// formula reading RAW a,b,c from LDS (bit-identical inputs => bit-identical
// d^2) and emits one (d_exact_bits, face) pair per (point, chunk). NO
// cheap-distance filtering anywhere (R5 lesson).
__global__ __launch_bounds__(PTS, 4) void scan_kernel(
    const float* __restrict__ tri, const float* __restrict__ pts,
    uint2* __restrict__ keys)
{
    constexpr int IM = ~(FC - 1);      // keep distance bits; low 6 bits = local face
    // Pair-interleaved constants: 22 f2 fields (11 float4) per triangle pair.
    // field f of pair pr lives at float offset pr*44 + 2*f + lane.
    __shared__ float4 SP4[(FC/2) * 11];
    __shared__ float4 SR[FC * 3];      // raw a,b,c per triangle for exact tail
    const int tid = threadIdx.x;
    const int pb = blockIdx.x, cb = blockIdx.y, bb = blockIdx.z;

    if (tid < FC) {   // one thread stages one triangle fully
        const float* g = tri + ((size_t)bb * F_ + (size_t)cb * FC + tid) * 9;
        float ax = g[0], ay = g[1], az = g[2];
        float bx = g[3], by = g[4], bz = g[5];
        float cx = g[6], cy = g[7], cz = g[8];
        float abx = bx - ax, aby = by - ay, abz = bz - az;
        float acx = cx - ax, acy = cy - ay, acz = cz - az;
        float daa = abx*abx + aby*aby + abz*abz;
        float dcc = acx*acx + acy*acy + acz*acz;
        float dac = abx*acx + aby*acy + abz*acz;
        float dbc = daa + dcc - 2.f*dac;
        float nn  = daa*dcc - dac*dac;
        float* w = (float*)SP4 + (tid >> 1) * 44 + (tid & 1);
        w[0]  = -ax;      w[2]  = -ay;      w[4]  = -az;
        w[6]  = abx;      w[8]  = aby;      w[10] = abz;
        w[12] = acx;      w[14] = acy;      w[16] = acz;
        w[18] = daa;      w[20] = dcc;      w[22] = -dac;
        w[24] = -daa;     w[26] = -dcc;     w[28] = -dbc;
        w[30] = daa - dac;
        w[32] = 1.f/daa;  w[34] = 1.f/dcc;  w[36] = 1.f/dbc;
        w[38] = 1.f/nn;   w[40] = nn;       w[42] = 0.f;
        SR[tid*3 + 0] = make_float4(ax, ay, az, 0.f);
        SR[tid*3 + 1] = make_float4(bx, by, bz, 0.f);
        SR[tid*3 + 2] = make_float4(cx, cy, cz, 0.f);
    }
    __syncthreads();

    const int q0 = pb * (PTS * PPT) + tid * PPT;
    const float* p0 = pts + ((size_t)bb * Q_ + q0) * 3;
    f4u l0 = *(const f4u*)(p0);
    f4u l1 = *(const f4u*)(p0 + 4);
    f4u l2 = *(const f4u*)(p0 + 8);
    float pxs[4] = {l0.x, l0.w, l1.z, l2.y};
    float pys[4] = {l0.y, l1.x, l1.w, l2.z};
    float pzs[4] = {l0.z, l1.y, l2.x, l2.w};

    f2 PX[4], PY[4], PZ[4];
    #pragma unroll
    for (int p = 0; p < 4; ++p) {
        PX[p].x = pxs[p]; PX[p].y = pxs[p];
        PY[p].x = pys[p]; PY[p].y = pys[p];
        PZ[p].x = pzs[p]; PZ[p].y = pzs[p];
    }
    f2 NEG1 = {-1.f, -1.f};

    int K0[4] = {0x7FFFFFFF, 0x7FFFFFFF, 0x7FFFFFFF, 0x7FFFFFFF};
    int K1[4] = {0x7FFFFFFF, 0x7FFFFFFF, 0x7FFFFFFF, 0x7FFFFFFF};

    for (int j = 0; j < FC/2; ++j) {
        const float4* r = SP4 + j * 11;
        float4 F0 = r[0], F1 = r[1], F2v = r[2], F3 = r[3], F4v = r[4];
        float4 F5 = r[5], F6 = r[6], F7 = r[7], F8 = r[8], F9 = r[9];
        float4 F10 = r[10];
        f2 nax = {F0.x, F0.y},  nay = {F0.z, F0.w};
        f2 naz = {F1.x, F1.y},  abx = {F1.z, F1.w};
        f2 aby = {F2v.x, F2v.y}, abz = {F2v.z, F2v.w};
        f2 acx = {F3.x, F3.y},  acy = {F3.z, F3.w};
        f2 acz = {F4v.x, F4v.y}, daa = {F4v.z, F4v.w};
        f2 dcc = {F5.x, F5.y},  ndac = {F5.z, F5.w};
        f2 ndaa = {F6.x, F6.y}, ndcc = {F6.z, F6.w};
        f2 ndbc = {F7.x, F7.y}, kk = {F7.z, F7.w};
        f2 rdaa = {F8.x, F8.y}, rdcc = {F8.z, F8.w};
        f2 rdbc = {F9.x, F9.y}, rnn = {F9.z, F9.w};
        f2 nn  = {F10.x, F10.y};

        #pragma unroll
        for (int p = 0; p < 4; ++p) {
            f2 d = tri_pair_dist(PX[p], PY[p], PZ[p],
                                 nax, nay, naz, abx, aby, abz, acx, acy, acz,
                                 daa, dcc, ndac, ndaa, ndcc, ndbc,
                                 kk, rdaa, rdcc, rdbc, rnn, nn, NEG1);
            int kx = (__float_as_int(d.x) & IM) | (2*j);
            int ky = (__float_as_int(d.y) & IM) | (2*j + 1);
            int lo = min(kx, ky), hi = max(kx, ky);
            int m  = max(K0[p], lo);
            K0[p] = min(K0[p], lo);
            K1[p] = min(min(K1[p], hi), m);
        }
    }

    // TAIL: exact np-order eval of both nominees per point (raw coords from LDS)
    #pragma unroll
    for (int p = 0; p < 4; ++p) {
        float px = pxs[p], py = pys[p], pz = pzs[p];
        float dbest = FLT_MAX; int fbest = 0x7FFFFFFF;
        #pragma unroll
        for (int j = 0; j < 2; ++j) {
            int lf = (j == 0 ? K0[p] : K1[p]) & (FC - 1);
            float4 ra = SR[lf*3 + 0];
            float4 rb = SR[lf*3 + 1];
            float4 rc = SR[lf*3 + 2];
            float u, v, w;
            bary_uvw(ra.x, ra.y, ra.z, rb.x, rb.y, rb.z, rc.x, rc.y, rc.z,
                     px, py, pz, u, v, w);
            float d2v;
            {
#pragma clang fp contract(off)
                float cpx = u*ra.x + v*rb.x + w*rc.x;
                float cpy = u*ra.y + v*rb.y + w*rc.y;
                float cpz = u*ra.z + v*rb.z + w*rc.z;
                float dx = cpx - px, dy = cpy - py, dz = cpz - pz;
                d2v = dx*dx + dy*dy + dz*dz;
            }
            int face = cb * FC + lf;
            if (d2v < dbest || (d2v == dbest && face < fbest)) { dbest = d2v; fbest = face; }
        }
        // point-major [b][q][chunk]: finalize reads coalesced uint4
        keys[((size_t)bb * Q_ + q0 + p) * NC + cb] = make_uint2(__float_as_uint(dbest), (uint)fbest);
    }
}

// ---------------------------------------------------------------------------
// Finalize: one WAVE per point; lane l loads chunks 2l,2l+1 exact pairs
// (coalesced uint4), wave lex-(d,face) reduce == jnp.argmin first occurrence
// (true winner is the exact-min of its chunk's top-2 pair, so it is the
// chunk representative). Lane 0 epilogue, contract-off np-order.
__global__ __launch_bounds__(256) void finalize_kernel(
    const float* __restrict__ tri, const float* __restrict__ pts,
    const float* __restrict__ nrm, const float* __restrict__ cmp,
    const int* __restrict__ faces,
    const uint2* __restrict__ keys,
    float* __restrict__ out)
{
#pragma clang fp contract(off)
    const int lane = threadIdx.x & 63;
    const int t = blockIdx.x * 4 + (threadIdx.x >> 6);
    const int bb = t >> 12;            // Q_ = 4096

    uint4 K = ((const uint4*)keys)[(size_t)t * (NC/2) + lane];
    float dbest = __uint_as_float(K.x); int fbest = (int)K.y;
    float d1v   = __uint_as_float(K.z); int f1v   = (int)K.w;
    if (d1v < dbest || (d1v == dbest && f1v < fbest)) { dbest = d1v; fbest = f1v; }
    for (int off = 32; off > 0; off >>= 1) {
        float od = __shfl_down(dbest, off);
        int   of = __shfl_down(fbest, off);
        if (od < dbest || (od == dbest && of < fbest)) { dbest = od; fbest = of; }
    }
    if (lane != 0) return;

    const float* pp = pts + (size_t)t * 3;
    float px = pp[0], py = pp[1], pz = pp[2];

    const int bestf = fbest;
    const float* tg = tri + ((size_t)bb * F_ + bestf) * 9;
    const float* ng = nrm + ((size_t)bb * F_ + bestf) * 9;
    const float* cg = cmp + ((size_t)bb * F_ + bestf) * 9;
    f4u TA = *(const f4u*)(tg), TB = *(const f4u*)(tg + 4);
    float TC = tg[8];
    f4u NA = *(const f4u*)(ng), NB = *(const f4u*)(ng + 4);
    float NCs = ng[8];
    f4u CA = *(const f4u*)(cg), CB = *(const f4u*)(cg + 4);
    float CC = cg[8];

    float u, v, w;
    bary_uvw(TA.x, TA.y, TA.z, TA.w, TB.x, TB.y, TB.z, TB.w, TC,
             px, py, pz, u, v, w);
    u = fminf(fmaxf(u, 0.f), 1.f);
    v = fminf(fmaxf(v, 0.f), 1.f);
    w = fminf(fmaxf(w, 0.f), 1.f);

    float cpx = u * TA.x + v * TA.w + w * TB.z;
    float cpy = u * TA.y + v * TB.x + w * TB.w;
    float cpz = u * TA.z + v * TB.y + w * TC;
    float nx  = u * NA.x + v * NA.w + w * NB.z;
    float ny  = u * NA.y + v * NB.x + w * NB.w;
    float nz  = u * NA.z + v * NB.y + w * NCs;
    float mx  = u * CA.x + v * CA.w + w * CB.z;
    float my  = u * CA.y + v * CB.x + w * CB.w;
    float mz  = u * CA.z + v * CB.y + w * CC;

    const size_t S3 = (size_t)B_ * Q_ * 3;
    out[(size_t)t * 3 + 0] = cpx - px;
    out[(size_t)t * 3 + 1] = cpy - py;
    out[(size_t)t * 3 + 2] = cpz - pz;
    out[S3 + (size_t)t * 3 + 0] = nx;
    out[S3 + (size_t)t * 3 + 1] = ny;
    out[S3 + (size_t)t * 3 + 2] = nz;
    out[2 * S3 + (size_t)t * 3 + 0] = mx;
    out[2 * S3 + (size_t)t * 3 + 1] = my;
    out[2 * S3 + (size_t)t * 3 + 2] = mz;

    int k = 0; float mm = u;
    if (v > mm) { mm = v; k = 1; }
    if (w > mm) { k = 2; }
    out[3 * S3 + t] = (float)faces[((size_t)bb * F_ + bestf) * 3 + k];
}

extern "C" void kernel_launch(void* const* d_in, const int* in_sizes, int n_in,
                              void* d_out, int out_size, void* d_ws, size_t ws_size,
                              hipStream_t stream) {
    const float* tri   = (const float*)d_in[0];
    const float* pts   = (const float*)d_in[1];
    const float* nrm   = (const float*)d_in[2];
    const float* cmp   = (const float*)d_in[3];
    const int*   faces = (const int*)d_in[4];
    float* out = (float*)d_out;

    uint2* keys = (uint2*)d_ws;   // [B][Q][NC] exact (d_bits, face) per chunk

    dim3 g1(Q_ / (PTS * PPT), NC, B_);
    scan_kernel<<<g1, PTS, 0, stream>>>(tri, pts, keys);
    finalize_kernel<<<(B_ * Q_) / 4, 256, 0, stream>>>(
        tri, pts, nrm, cmp, faces, keys, out);
}